// Round 7
// baseline (1244.196 us; speedup 1.0000x reference)
//
#include <hip/hip_runtime.h>
#include <hip/hip_bf16.h>
#include <math.h>

typedef __hip_bfloat16 bf16;
typedef unsigned short u16;

__device__ __forceinline__ float us2f(u16 u) { return __uint_as_float(((unsigned)u) << 16); }
__device__ __forceinline__ u16 f2us(float f) { bf16 h = __float2bfloat16(f); return *(u16*)&h; }

__device__ __forceinline__ float wave_bcast_sum(float v) {
#pragma unroll
    for (int off = 32; off > 0; off >>= 1) v += __shfl_down(v, off);
    return __shfl(v, 0);
}

// ---------------------------------------------------------------------------
// LN1 + roll(-3,-3,-3) + window partition. f32 in -> bf16 out (window order).
// One wave per token; 3 channels per lane.
// ---------------------------------------------------------------------------
__global__ __launch_bounds__(256) void k_ln1_winpart(
    const float* __restrict__ x, const float* __restrict__ g, const float* __restrict__ b,
    u16* __restrict__ out)
{
    int lane = threadIdx.x & 63;
    int t = blockIdx.x * 4 + (threadIdx.x >> 6);
    int bidx = t / (64 * 343);
    int r = t - bidx * (64 * 343);
    int w = r / 343;
    int n = r - w * 343;
    int wd = w >> 4, wh = (w >> 2) & 3, ww = w & 3;
    int i = n / 49, rem = n - i * 49;
    int j = rem / 7, k = rem - j * 7;
    int sd = wd * 7 + i + 3; if (sd >= 28) sd -= 28;
    int sh = wh * 7 + j + 3; if (sh >= 28) sh -= 28;
    int sw = ww * 7 + k + 3; if (sw >= 28) sw -= 28;
    size_t src = ((((size_t)bidx * 28 + sd) * 28 + sh) * 28 + sw) * 192;
    float v0 = x[src + lane], v1 = x[src + lane + 64], v2 = x[src + lane + 128];
    float s  = wave_bcast_sum(v0 + v1 + v2);
    float mu = s * (1.0f / 192.0f);
    float s2 = wave_bcast_sum(v0 * v0 + v1 * v1 + v2 * v2);
    float rs = rsqrtf(s2 * (1.0f / 192.0f) - mu * mu + 1e-5f);
    u16* op = out + (size_t)t * 192;
    op[lane]       = f2us((v0 - mu) * rs * g[lane]       + b[lane]);
    op[lane + 64]  = f2us((v1 - mu) * rs * g[lane + 64]  + b[lane + 64]);
    op[lane + 128] = f2us((v2 - mu) * rs * g[lane + 128] + b[lane + 128]);
}

// ---------------------------------------------------------------------------
// LN2 over f32 residual x1 [M,192] (in d_out) -> bf16
// ---------------------------------------------------------------------------
__global__ __launch_bounds__(256) void k_ln2(
    const float* __restrict__ x1, const float* __restrict__ g, const float* __restrict__ b,
    u16* __restrict__ out)
{
    int lane = threadIdx.x & 63;
    int t = blockIdx.x * 4 + (threadIdx.x >> 6);
    const float* xp = x1 + (size_t)t * 192;
    float v0 = xp[lane], v1 = xp[lane + 64], v2 = xp[lane + 128];
    float s  = wave_bcast_sum(v0 + v1 + v2);
    float mu = s * (1.0f / 192.0f);
    float s2 = wave_bcast_sum(v0 * v0 + v1 * v1 + v2 * v2);
    float rs = rsqrtf(s2 * (1.0f / 192.0f) - mu * mu + 1e-5f);
    u16* op = out + (size_t)t * 192;
    op[lane]       = f2us((v0 - mu) * rs * g[lane]       + b[lane]);
    op[lane + 64]  = f2us((v1 - mu) * rs * g[lane + 64]  + b[lane + 64]);
    op[lane + 128] = f2us((v2 - mu) * rs * g[lane + 128] + b[lane + 128]);
}

// ---------------------------------------------------------------------------
// GEMM: out[m,n] = epi( sum_k A[m,k]*W[n,k] + bias[n] ).  A bf16 [M,K],
// W/bias f32 [Nc,K]. 64x64 tile, BK=16, 256 thr, 4x4/thread.
// ACT: 0 none, 1 exact GELU.  OUT: 1 bf16, 2 f32 with f32 resid add.
// M%64==0, Nc%64==0, K%16==0.
// ---------------------------------------------------------------------------
template<int ACT, int OUT>
__global__ __launch_bounds__(256) void k_gemm(
    const u16* __restrict__ A, const float* __restrict__ W, const float* __restrict__ bias,
    u16* __restrict__ outB, float* __restrict__ outF, const float* __restrict__ resid,
    int M, int Nc, int K)
{
    __shared__ __align__(16) float As[16][68];
    __shared__ __align__(16) float Bs[16][68];
    int tid = threadIdx.x;
    int tx = tid & 15, ty = tid >> 4;
    int m0 = blockIdx.y << 6, n0 = blockIdx.x << 6;
    int lrow = tid >> 2;        // 0..63
    int lk = (tid & 3) << 2;    // 0,4,8,12
    float acc[4][4] = {};
    for (int k0 = 0; k0 < K; k0 += 16) {
        ushort4 av = *(const ushort4*)(A + (size_t)(m0 + lrow) * K + k0 + lk);
        float4  wv = *(const float4*)(W + (size_t)(n0 + lrow) * K + k0 + lk);
        As[lk + 0][lrow] = us2f(av.x); As[lk + 1][lrow] = us2f(av.y);
        As[lk + 2][lrow] = us2f(av.z); As[lk + 3][lrow] = us2f(av.w);
        Bs[lk + 0][lrow] = wv.x; Bs[lk + 1][lrow] = wv.y;
        Bs[lk + 2][lrow] = wv.z; Bs[lk + 3][lrow] = wv.w;
        __syncthreads();
#pragma unroll
        for (int kk = 0; kk < 16; kk++) {
            float4 a4 = *(const float4*)&As[kk][ty << 2];
            float4 b4 = *(const float4*)&Bs[kk][tx << 2];
            float a[4] = {a4.x, a4.y, a4.z, a4.w};
            float bb[4] = {b4.x, b4.y, b4.z, b4.w};
#pragma unroll
            for (int ii = 0; ii < 4; ii++)
#pragma unroll
                for (int jj = 0; jj < 4; jj++)
                    acc[ii][jj] = fmaf(a[ii], bb[jj], acc[ii][jj]);
        }
        __syncthreads();
    }
#pragma unroll
    for (int ii = 0; ii < 4; ii++) {
        int m = m0 + (ty << 2) + ii;
#pragma unroll
        for (int jj = 0; jj < 4; jj++) {
            int n = n0 + (tx << 2) + jj;
            float v = acc[ii][jj] + bias[n];
            if (ACT == 1) v = 0.5f * v * (1.0f + erff(v * 0.70710678118654752f));
            size_t off = (size_t)m * Nc + n;
            if (OUT == 1) outB[off] = f2us(v);
            else outF[off] = resid[off] + v;
        }
    }
}

// ---------------------------------------------------------------------------
// Fused windowed attention. One block per (head, window, batch).
// qkv bf16 [M,576]; o_win bf16 [M,192]; rpb f32 [2197,6].
// bias idx = t[n]-t[m]+1098, t = i*169+j*13+k.
// ---------------------------------------------------------------------------
__global__ __launch_bounds__(256) void k_attn(
    const u16* __restrict__ qkv, const float* __restrict__ rpb, u16* __restrict__ o_win)
{
    int head = blockIdx.x;
    int w = blockIdx.y;
    int bidx = blockIdx.z;
    __shared__ __align__(16) u16 Ks[343 * 32];
    __shared__ __align__(16) u16 Vs[343 * 32];
    __shared__ float rpbs[2197];
    __shared__ short tcode[343];
    __shared__ unsigned char lab[343];
    int tid = threadIdx.x;
    size_t base = ((size_t)(bidx * 64 + w)) * 343;
    for (int i = tid; i < 2744; i += 256) {
        int m = i >> 3;
        int d4 = (i & 7) << 2;
        size_t off = (base + m) * 576 + head * 32 + d4;
        *(ushort4*)&Ks[(m << 5) + d4] = *(const ushort4*)(qkv + off + 192);
        *(ushort4*)&Vs[(m << 5) + d4] = *(const ushort4*)(qkv + off + 384);
    }
    for (int i = tid; i < 2197; i += 256)
        rpbs[i] = rpb[(size_t)i * 6 + head];
    int wd = w >> 4, wh = (w >> 2) & 3, ww = w & 3;
    for (int n = tid; n < 343; n += 256) {
        int i = n / 49, rem = n - i * 49;
        int j = rem / 7, k = rem - j * 7;
        tcode[n] = (short)(i * 169 + j * 13 + k);
        int gd = wd * 7 + i, gh = wh * 7 + j, gw = ww * 7 + k;
        int ld_ = (gd < 21) ? 0 : ((gd < 25) ? 1 : 2);
        int lh_ = (gh < 21) ? 0 : ((gh < 25) ? 1 : 2);
        int lw_ = (gw < 21) ? 0 : ((gw < 25) ? 1 : 2);
        lab[n] = (unsigned char)(ld_ * 9 + lh_ * 3 + lw_);
    }
    __syncthreads();
    const float scale = 0.17677669529663687f; // 1/sqrt(32)
    for (int n = tid; n < 343; n += 256) {
        float q[32];
        const u16* qp = qkv + (base + n) * 576 + head * 32;
#pragma unroll
        for (int d = 0; d < 32; d++) q[d] = us2f(qp[d]) * scale;
        int tn = (int)tcode[n] + 1098;
        int ln_ = lab[n];
        float o[32];
#pragma unroll
        for (int d = 0; d < 32; d++) o[d] = 0.0f;
        float sum = 0.0f;
        for (int m = 0; m < 343; m++) {
            const u16* kp = &Ks[m << 5];
            float s = 0.0f;
#pragma unroll
            for (int d = 0; d < 32; d++) s = fmaf(q[d], us2f(kp[d]), s);
            s += rpbs[tn - (int)tcode[m]];
            if (lab[m] != ln_) s -= 100.0f;
            float p = __expf(s);
            sum += p;
            const u16* vp = &Vs[m << 5];
#pragma unroll
            for (int d = 0; d < 32; d++) o[d] = fmaf(p, us2f(vp[d]), o[d]);
        }
        float inv = 1.0f / sum;
        u16* op = o_win + (base + n) * 192 + head * 32;
#pragma unroll
        for (int d = 0; d < 32; d++) op[d] = f2us(o[d] * inv);
    }
}

// ---------------------------------------------------------------------------
// Window reverse + roll(+3) + residual: x1 = x + rev(projw), f32 into d_out.
// ---------------------------------------------------------------------------
__global__ __launch_bounds__(256) void k_add_winrev(
    const float* __restrict__ x, const u16* __restrict__ projw, float* __restrict__ x1)
{
    int idx = blockIdx.x * 256 + threadIdx.x;
    int c = idx % 192;
    int tok = idx / 192;
    int sw_ = tok % 28, t1 = tok / 28;
    int sh_ = t1 % 28, t2 = t1 / 28;
    int sd_ = t2 % 28, bidx = t2 / 28;
    int rd = sd_ + 25; if (rd >= 28) rd -= 28;   // (d-3) mod 28
    int rh = sh_ + 25; if (rh >= 28) rh -= 28;
    int rw = sw_ + 25; if (rw >= 28) rw -= 28;
    int wd = rd / 7, i = rd - wd * 7;
    int wh = rh / 7, j = rh - wh * 7;
    int ww = rw / 7, k = rw - ww * 7;
    int w = (wd << 4) + (wh << 2) + ww;
    int n = (i * 7 + j) * 7 + k;
    size_t src = (((size_t)(bidx * 64 + w)) * 343 + n) * 192 + c;
    x1[idx] = x[idx] + us2f(projw[src]);
}

// ---------------------------------------------------------------------------
extern "C" void kernel_launch(void* const* d_in, const int* in_sizes, int n_in,
                              void* d_out, int out_size, void* d_ws, size_t ws_size,
                              hipStream_t stream)
{
    const float* x      = (const float*)d_in[0];
    const float* ln1_g  = (const float*)d_in[1];
    const float* ln1_b  = (const float*)d_in[2];
    const float* qkv_w  = (const float*)d_in[3];
    const float* qkv_b  = (const float*)d_in[4];
    const float* rpb    = (const float*)d_in[5];
    const float* proj_w = (const float*)d_in[6];
    const float* proj_b = (const float*)d_in[7];
    const float* ln2_g  = (const float*)d_in[8];
    const float* ln2_b  = (const float*)d_in[9];
    const float* fc1_w  = (const float*)d_in[10];
    const float* fc1_b  = (const float*)d_in[11];
    const float* fc2_w  = (const float*)d_in[12];
    const float* fc2_b  = (const float*)d_in[13];

    const int M = 43904;                   // tokens = B*nW*N
    const size_t MC  = (size_t)M * 192;
    const size_t MC2 = MC * 2;             // bytes of a bf16 [M,192] buffer

    // ws (67.4 MB peak, proven): hA [0,MC2) ; B-region [MC2, MC2+M*576*2)
    char* ws = (char*)d_ws;
    u16* hA    = (u16*)ws;                 // hwin -> owin -> h2
    u16* qkvb  = (u16*)(ws + MC2);
    u16* projw = (u16*)(ws + MC2);         // overlays dead qkvb
    u16* gbuf  = (u16*)(ws + MC2);         // overlays dead projw (MLP hidden chunk)
    float* out = (float*)d_out;            // x1 residual stream, then final output

    k_ln1_winpart<<<M / 4, 256, 0, stream>>>(x, ln1_g, ln1_b, hA);
    k_gemm<0, 1><<<dim3(9, 686), 256, 0, stream>>>(hA, qkv_w, qkv_b, qkvb, nullptr, nullptr, M, 576, 192);
    k_attn<<<dim3(6, 64, 2), 256, 0, stream>>>(qkvb, rpb, hA);
    k_gemm<0, 1><<<dim3(3, 686), 256, 0, stream>>>(hA, proj_w, proj_b, projw, nullptr, nullptr, M, 192, 192);
    k_add_winrev<<<(int)(MC / 256), 256, 0, stream>>>(x, projw, out);
    k_ln2<<<M / 4, 256, 0, stream>>>(out, ln2_g, ln2_b, hA);
    // MLP: 7 chunks of 6272 rows; hidden bf16 [6272,768] = 9.6 MB in gbuf
    const int CH = 6272;
    for (int c = 0; c < 7; c++) {
        size_t r0 = (size_t)c * CH;
        k_gemm<1, 1><<<dim3(12, CH / 64), 256, 0, stream>>>(hA + r0 * 192, fc1_w, fc1_b, gbuf, nullptr, nullptr, CH, 768, 192);
        k_gemm<0, 2><<<dim3(3, CH / 64), 256, 0, stream>>>(gbuf, fc2_w, fc2_b, nullptr, out + r0 * 192, out + r0 * 192, CH, 192, 768);
    }
}

// Round 8
// 774.812 us; speedup vs baseline: 1.6058x; 1.6058x over previous
//
#include <hip/hip_runtime.h>
#include <hip/hip_bf16.h>
#include <math.h>

typedef __hip_bfloat16 bf16;
typedef unsigned short u16;
typedef __attribute__((ext_vector_type(8))) short bf16x8;
typedef __attribute__((ext_vector_type(4))) float f32x4;

__device__ __forceinline__ float us2f(u16 u) { return __uint_as_float(((unsigned)u) << 16); }
__device__ __forceinline__ u16 f2us(float f) { bf16 h = __float2bfloat16(f); return *(u16*)&h; }

__device__ __forceinline__ float wave_bcast_sum(float v) {
#pragma unroll
    for (int off = 32; off > 0; off >>= 1) v += __shfl_down(v, off);
    return __shfl(v, 0);
}

// ---------------------------------------------------------------------------
// f32 -> bf16 elementwise conversion (for weights)
// ---------------------------------------------------------------------------
__global__ __launch_bounds__(256) void k_f2b(const float* __restrict__ in, u16* __restrict__ out, int n) {
    int i = blockIdx.x * 256 + threadIdx.x;
    if (i < n) out[i] = f2us(in[i]);
}

// ---------------------------------------------------------------------------
// LN1 + roll(-3,-3,-3) + window partition. f32 in -> bf16 out (window order).
// ---------------------------------------------------------------------------
__global__ __launch_bounds__(256) void k_ln1_winpart(
    const float* __restrict__ x, const float* __restrict__ g, const float* __restrict__ b,
    u16* __restrict__ out)
{
    int lane = threadIdx.x & 63;
    int t = blockIdx.x * 4 + (threadIdx.x >> 6);
    int bidx = t / (64 * 343);
    int r = t - bidx * (64 * 343);
    int w = r / 343;
    int n = r - w * 343;
    int wd = w >> 4, wh = (w >> 2) & 3, ww = w & 3;
    int i = n / 49, rem = n - i * 49;
    int j = rem / 7, k = rem - j * 7;
    int sd = wd * 7 + i + 3; if (sd >= 28) sd -= 28;
    int sh = wh * 7 + j + 3; if (sh >= 28) sh -= 28;
    int sw = ww * 7 + k + 3; if (sw >= 28) sw -= 28;
    size_t src = ((((size_t)bidx * 28 + sd) * 28 + sh) * 28 + sw) * 192;
    float v0 = x[src + lane], v1 = x[src + lane + 64], v2 = x[src + lane + 128];
    float s  = wave_bcast_sum(v0 + v1 + v2);
    float mu = s * (1.0f / 192.0f);
    float s2 = wave_bcast_sum(v0 * v0 + v1 * v1 + v2 * v2);
    float rs = rsqrtf(s2 * (1.0f / 192.0f) - mu * mu + 1e-5f);
    u16* op = out + (size_t)t * 192;
    op[lane]       = f2us((v0 - mu) * rs * g[lane]       + b[lane]);
    op[lane + 64]  = f2us((v1 - mu) * rs * g[lane + 64]  + b[lane + 64]);
    op[lane + 128] = f2us((v2 - mu) * rs * g[lane + 128] + b[lane + 128]);
}

// ---------------------------------------------------------------------------
// LN2 over f32 residual x1 [M,192] (in d_out) -> bf16
// ---------------------------------------------------------------------------
__global__ __launch_bounds__(256) void k_ln2(
    const float* __restrict__ x1, const float* __restrict__ g, const float* __restrict__ b,
    u16* __restrict__ out)
{
    int lane = threadIdx.x & 63;
    int t = blockIdx.x * 4 + (threadIdx.x >> 6);
    const float* xp = x1 + (size_t)t * 192;
    float v0 = xp[lane], v1 = xp[lane + 64], v2 = xp[lane + 128];
    float s  = wave_bcast_sum(v0 + v1 + v2);
    float mu = s * (1.0f / 192.0f);
    float s2 = wave_bcast_sum(v0 * v0 + v1 * v1 + v2 * v2);
    float rs = rsqrtf(s2 * (1.0f / 192.0f) - mu * mu + 1e-5f);
    u16* op = out + (size_t)t * 192;
    op[lane]       = f2us((v0 - mu) * rs * g[lane]       + b[lane]);
    op[lane + 64]  = f2us((v1 - mu) * rs * g[lane + 64]  + b[lane + 64]);
    op[lane + 128] = f2us((v2 - mu) * rs * g[lane + 128] + b[lane + 128]);
}

// ---------------------------------------------------------------------------
// MFMA GEMM: out[m,n] = epi( sum_k A[m,k]*W[n,k] + bias[n] )
// A bf16 [M,K], W bf16 [Nc,K], bias f32. Tile BM=128, BN=64, BK=32.
// 256 thr = 4 waves; wave w owns rows [w*32,(w+1)*32) as 2x(16) x 4x(16) mfma
// 16x16x32 tiles. Frag layouts per m89/m91-verified mapping:
//   A-op: A[m=lane&15][k=(lane>>4)*8+j] ; C/D: row=(lane>>4)*4+r, col=lane&15.
// M%128==0, Nc%64==0, K%32==0.
// ACT: 0 none, 1 exact GELU. OUT: 1 bf16, 2 f32 + f32 resid add (in-place ok).
// ---------------------------------------------------------------------------
template<int ACT, int OUT>
__global__ __launch_bounds__(256) void k_gemm_mfma(
    const u16* __restrict__ A, const u16* __restrict__ W, const float* __restrict__ bias,
    u16* __restrict__ outB, float* __restrict__ outF, const float* __restrict__ resid,
    int M, int Nc, int K)
{
    __shared__ __align__(16) u16 As[128 * 32];
    __shared__ __align__(16) u16 Bs[64 * 32];
    int tid = threadIdx.x;
    int lane = tid & 63, wv = tid >> 6;
    int quad = lane >> 4, l16 = lane & 15;
    int m0 = blockIdx.y << 7, n0 = blockIdx.x << 6;

    f32x4 acc[2][4] = {};
    int rowA0 = tid >> 2;                 // 0..63
    int rowA1 = rowA0 + 64;               // 64..127
    int koff = (tid & 3) << 3;            // 0,8,16,24

    for (int k0 = 0; k0 < K; k0 += 32) {
        uint4 a0 = *(const uint4*)(A + (size_t)(m0 + rowA0) * K + k0 + koff);
        uint4 a1 = *(const uint4*)(A + (size_t)(m0 + rowA1) * K + k0 + koff);
        uint4 b0 = *(const uint4*)(W + (size_t)(n0 + rowA0) * K + k0 + koff);
        __syncthreads();
        *(uint4*)&As[rowA0 * 32 + koff] = a0;
        *(uint4*)&As[rowA1 * 32 + koff] = a1;
        *(uint4*)&Bs[rowA0 * 32 + koff] = b0;
        __syncthreads();
        bf16x8 af[2], bfr[4];
#pragma unroll
        for (int mt = 0; mt < 2; mt++)
            af[mt] = *(const bf16x8*)&As[(wv * 32 + mt * 16 + l16) * 32 + quad * 8];
#pragma unroll
        for (int nt = 0; nt < 4; nt++)
            bfr[nt] = *(const bf16x8*)&Bs[(nt * 16 + l16) * 32 + quad * 8];
#pragma unroll
        for (int mt = 0; mt < 2; mt++)
#pragma unroll
            for (int nt = 0; nt < 4; nt++)
                acc[mt][nt] = __builtin_amdgcn_mfma_f32_16x16x32_bf16(af[mt], bfr[nt], acc[mt][nt], 0, 0, 0);
    }
#pragma unroll
    for (int mt = 0; mt < 2; mt++) {
#pragma unroll
        for (int nt = 0; nt < 4; nt++) {
#pragma unroll
            for (int r = 0; r < 4; r++) {
                int m = m0 + wv * 32 + mt * 16 + quad * 4 + r;
                int n = n0 + nt * 16 + l16;
                float v = acc[mt][nt][r] + bias[n];
                if (ACT == 1) v = 0.5f * v * (1.0f + erff(v * 0.70710678118654752f));
                size_t off = (size_t)m * Nc + n;
                if (OUT == 1) outB[off] = f2us(v);
                else outF[off] = resid[off] + v;
            }
        }
    }
}

// ---------------------------------------------------------------------------
// Fused windowed attention (unchanged from R7 — proven).
// ---------------------------------------------------------------------------
__global__ __launch_bounds__(256) void k_attn(
    const u16* __restrict__ qkv, const float* __restrict__ rpb, u16* __restrict__ o_win)
{
    int head = blockIdx.x;
    int w = blockIdx.y;
    int bidx = blockIdx.z;
    __shared__ __align__(16) u16 Ks[343 * 32];
    __shared__ __align__(16) u16 Vs[343 * 32];
    __shared__ float rpbs[2197];
    __shared__ short tcode[343];
    __shared__ unsigned char lab[343];
    int tid = threadIdx.x;
    size_t base = ((size_t)(bidx * 64 + w)) * 343;
    for (int i = tid; i < 2744; i += 256) {
        int m = i >> 3;
        int d4 = (i & 7) << 2;
        size_t off = (base + m) * 576 + head * 32 + d4;
        *(ushort4*)&Ks[(m << 5) + d4] = *(const ushort4*)(qkv + off + 192);
        *(ushort4*)&Vs[(m << 5) + d4] = *(const ushort4*)(qkv + off + 384);
    }
    for (int i = tid; i < 2197; i += 256)
        rpbs[i] = rpb[(size_t)i * 6 + head];
    int wd = w >> 4, wh = (w >> 2) & 3, ww = w & 3;
    for (int n = tid; n < 343; n += 256) {
        int i = n / 49, rem = n - i * 49;
        int j = rem / 7, k = rem - j * 7;
        tcode[n] = (short)(i * 169 + j * 13 + k);
        int gd = wd * 7 + i, gh = wh * 7 + j, gw = ww * 7 + k;
        int ld_ = (gd < 21) ? 0 : ((gd < 25) ? 1 : 2);
        int lh_ = (gh < 21) ? 0 : ((gh < 25) ? 1 : 2);
        int lw_ = (gw < 21) ? 0 : ((gw < 25) ? 1 : 2);
        lab[n] = (unsigned char)(ld_ * 9 + lh_ * 3 + lw_);
    }
    __syncthreads();
    const float scale = 0.17677669529663687f; // 1/sqrt(32)
    for (int n = tid; n < 343; n += 256) {
        float q[32];
        const u16* qp = qkv + (base + n) * 576 + head * 32;
#pragma unroll
        for (int d = 0; d < 32; d++) q[d] = us2f(qp[d]) * scale;
        int tn = (int)tcode[n] + 1098;
        int ln_ = lab[n];
        float o[32];
#pragma unroll
        for (int d = 0; d < 32; d++) o[d] = 0.0f;
        float sum = 0.0f;
        for (int m = 0; m < 343; m++) {
            const u16* kp = &Ks[m << 5];
            float s = 0.0f;
#pragma unroll
            for (int d = 0; d < 32; d++) s = fmaf(q[d], us2f(kp[d]), s);
            s += rpbs[tn - (int)tcode[m]];
            if (lab[m] != ln_) s -= 100.0f;
            float p = __expf(s);
            sum += p;
            const u16* vp = &Vs[m << 5];
#pragma unroll
            for (int d = 0; d < 32; d++) o[d] = fmaf(p, us2f(vp[d]), o[d]);
        }
        float inv = 1.0f / sum;
        u16* op = o_win + (base + n) * 192 + head * 32;
#pragma unroll
        for (int d = 0; d < 32; d++) op[d] = f2us(o[d] * inv);
    }
}

// ---------------------------------------------------------------------------
// Window reverse + roll(+3) + residual: x1 = x + rev(projw), f32 into d_out.
// ---------------------------------------------------------------------------
__global__ __launch_bounds__(256) void k_add_winrev(
    const float* __restrict__ x, const u16* __restrict__ projw, float* __restrict__ x1)
{
    int idx = blockIdx.x * 256 + threadIdx.x;
    int c = idx % 192;
    int tok = idx / 192;
    int sw_ = tok % 28, t1 = tok / 28;
    int sh_ = t1 % 28, t2 = t1 / 28;
    int sd_ = t2 % 28, bidx = t2 / 28;
    int rd = sd_ + 25; if (rd >= 28) rd -= 28;   // (d-3) mod 28
    int rh = sh_ + 25; if (rh >= 28) rh -= 28;
    int rw = sw_ + 25; if (rw >= 28) rw -= 28;
    int wd = rd / 7, i = rd - wd * 7;
    int wh = rh / 7, j = rh - wh * 7;
    int ww = rw / 7, k = rw - ww * 7;
    int w = (wd << 4) + (wh << 2) + ww;
    int n = (i * 7 + j) * 7 + k;
    size_t src = (((size_t)(bidx * 64 + w)) * 343 + n) * 192 + c;
    x1[idx] = x[idx] + us2f(projw[src]);
}

// ---------------------------------------------------------------------------
extern "C" void kernel_launch(void* const* d_in, const int* in_sizes, int n_in,
                              void* d_out, int out_size, void* d_ws, size_t ws_size,
                              hipStream_t stream)
{
    const float* x      = (const float*)d_in[0];
    const float* ln1_g  = (const float*)d_in[1];
    const float* ln1_b  = (const float*)d_in[2];
    const float* qkv_w  = (const float*)d_in[3];
    const float* qkv_b  = (const float*)d_in[4];
    const float* rpb    = (const float*)d_in[5];
    const float* proj_w = (const float*)d_in[6];
    const float* proj_b = (const float*)d_in[7];
    const float* ln2_g  = (const float*)d_in[8];
    const float* ln2_b  = (const float*)d_in[9];
    const float* fc1_w  = (const float*)d_in[10];
    const float* fc1_b  = (const float*)d_in[11];
    const float* fc2_w  = (const float*)d_in[12];
    const float* fc2_b  = (const float*)d_in[13];

    const int M = 43904;                   // tokens = B*nW*N (343 * 128-row tiles)
    const size_t MC  = (size_t)M * 192;
    const size_t MC2 = MC * 2;             // bytes of a bf16 [M,192] buffer

    // ws layout (peak == R7's proven 67.4MB footprint):
    //   hA    [0, MC2)            : hwin -> owin -> h2 (bf16 [M,192])
    //   qkvb  [MC2, MC2+50.6MB)   : qkv bf16 [M,576]; after attn recycled:
    //     projw   [MC2, MC2+16.9MB)      bf16 [M,192]
    //     gbuf    [MC2, MC2+9.7MB)       MLP hidden chunk bf16 [6272,768]
    //     fc1_wb  [MC2+17MB, +294912)    bf16 weights (converted after attn)
    //     fc2_wb  [MC2+17MB+294912, ...)
    // d_out (f32 33.7MB): first 590KB used as u16 scratch for qkv_wb/proj_wb
    // during phase 1 (dead once add_winrev overwrites d_out with x1).
    char* ws = (char*)d_ws;
    u16* hA     = (u16*)ws;
    u16* qkvb   = (u16*)(ws + MC2);
    u16* projw  = (u16*)(ws + MC2);
    u16* gbuf   = (u16*)(ws + MC2);
    u16* fc1_wb = (u16*)(ws + MC2 + 17u * 1024 * 1024);
    u16* fc2_wb = (u16*)(ws + MC2 + 17u * 1024 * 1024 + 294912);
    float* out  = (float*)d_out;
    u16* qkv_wb  = (u16*)d_out;            // 110592 u16
    u16* proj_wb = (u16*)d_out + 110592;   //  36864 u16

    // Phase 1: LN1, QKV (MFMA), attention
    k_f2b<<<432, 256, 0, stream>>>(qkv_w, qkv_wb, 110592);
    k_f2b<<<144, 256, 0, stream>>>(proj_w, proj_wb, 36864);
    k_ln1_winpart<<<M / 4, 256, 0, stream>>>(x, ln1_g, ln1_b, hA);
    k_gemm_mfma<0, 1><<<dim3(9, 343), 256, 0, stream>>>(hA, qkv_wb, qkv_b, qkvb, nullptr, nullptr, M, 576, 192);
    k_attn<<<dim3(6, 64, 2), 256, 0, stream>>>(qkvb, rpb, hA);
    // fc weights into dead qkvb tail (must be after attn)
    k_f2b<<<576, 256, 0, stream>>>(fc1_w, fc1_wb, 147456);
    k_f2b<<<576, 256, 0, stream>>>(fc2_w, fc2_wb, 147456);
    // proj (MFMA), window-reverse + residual
    k_gemm_mfma<0, 1><<<dim3(3, 343), 256, 0, stream>>>(hA, proj_wb, proj_b, projw, nullptr, nullptr, M, 192, 192);
    k_add_winrev<<<(int)(MC / 256), 256, 0, stream>>>(x, projw, out);
    // Phase 2: LN2 + MLP (MFMA), 7 chunks of 6272 rows (49 x 128)
    k_ln2<<<M / 4, 256, 0, stream>>>(out, ln2_g, ln2_b, hA);
    const int CH = 6272;
    for (int c = 0; c < 7; c++) {
        size_t r0 = (size_t)c * CH;
        k_gemm_mfma<1, 1><<<dim3(12, 49), 256, 0, stream>>>(hA + r0 * 192, fc1_wb, fc1_b, gbuf, nullptr, nullptr, CH, 768, 192);
        k_gemm_mfma<0, 2><<<dim3(3, 49), 256, 0, stream>>>(gbuf, fc2_wb, fc2_b, nullptr, out + r0 * 192, out + r0 * 192, CH, 192, 768);
    }
}